// Round 10
// baseline (89.465 us; speedup 1.0000x reference)
//
#include <hip/hip_runtime.h>
#include <hip/hip_bf16.h>
#include <cstdint>

// GAT fused layer: B=4, N=2048, F=128, H=8, HD=16, all fp32 I/O.
// Identity: exp(leaky(si+sj)) = max(exp(si)exp(sj), exp(.2si)exp(.2sj))
// gat v10: LDS-staged 2-phase pipeline (m97-style, plain HIP):
//   per chunk of 64 j: {load next chunk -> regs | compute current from LDS |
//   ds_write regs -> other buffer | barrier}. Global loads get a full
//   compute phase of latency cover, enforced by the barrier (register
//   prefetch failed r4-r9: compiler sinks loads). V in LDS with XOR slot
//   swizzle (2-way bank alias = free). Masks: tmask wave-uniform s_load +
//   inverse_ballot (r9-proven). Aggregation + row-sum via
//   mfma_f32_16x16x32_bf16 (B=ones). Fused out-proj + ELU.

typedef float f32x2 __attribute__((ext_vector_type(2)));
typedef float f32x4 __attribute__((ext_vector_type(4)));
typedef __bf16 bf16x8 __attribute__((ext_vector_type(8)));
typedef unsigned long long u64;

__device__ __forceinline__ float lsel(float v, u64 m, u64 lanebit) {
#if __has_builtin(__builtin_amdgcn_inverse_ballot_w64)
    (void)lanebit;
    return __builtin_amdgcn_inverse_ballot_w64(m) ? v : 0.0f;
#else
    return (m & lanebit) ? v : 0.0f;
#endif
}

__global__ __launch_bounds__(256)
void prep_kernel(const float* __restrict__ x, const float* __restrict__ W,
                 const float* __restrict__ a, const float* __restrict__ Wo,
                 const int* __restrict__ adj,
                 unsigned short* __restrict__ wxT,
                 float2* __restrict__ EI,
                 float* __restrict__ EjT, float* __restrict__ Ej5T,
                 float* __restrict__ WoT,
                 u64* __restrict__ bits)
{
    const int t = threadIdx.x;

    if (blockIdx.x >= 1025) {
        // ---- row-major pack: 2048 blocks x 4 rows (proven)
        const int wid = (blockIdx.x - 1025) * 4 + (t >> 6);  // row 0..8191
        const int lane = t & 63;
        const int* row = adj + (size_t)wid * 2048;
        u64* brow = bits + (size_t)wid * 32;
        #pragma unroll 2
        for (int it = 0; it < 8; ++it) {
            const int base = it * 256;
            const u64 w0 = __ballot(row[base + lane] != 0);
            const u64 w1 = __ballot(row[base + 64 + lane] != 0);
            const u64 w2 = __ballot(row[base + 128 + lane] != 0);
            const u64 w3 = __ballot(row[base + 192 + lane] != 0);
            if (lane == 0) {
                ulonglong2 p0; p0.x = w0; p0.y = w1;
                ulonglong2 p1; p1.x = w2; p1.y = w3;
                *reinterpret_cast<ulonglong2*>(&brow[it * 4])     = p0;
                *reinterpret_cast<ulonglong2*>(&brow[it * 4 + 2]) = p1;
            }
        }
        return;
    }

    // ---- proj: blocks 0..1024 (t<128 active)
    const int blk = blockIdx.x;
    if (blk == 1024) {
        if (t < 128)
            for (int k = 0; k < 128; ++k)
                WoT[k * 128 + t] = Wo[t * 128 + k];
        return;
    }
    __shared__ float xl[8 * 128];
    __shared__ float xw[8 * 128];
    const int row0 = blk * 8;
    if (t < 128) {
        #pragma unroll
        for (int r = 0; r < 8; ++r)
            xl[r * 128 + t] = x[(size_t)(row0 + r) * 128 + t];
    }
    __syncthreads();

    if (t < 128) {
        float acc[8] = {0.f, 0.f, 0.f, 0.f, 0.f, 0.f, 0.f, 0.f};
        for (int k = 0; k < 128; k += 4) {
            const float w0 = W[(k + 0) * 128 + t];
            const float w1 = W[(k + 1) * 128 + t];
            const float w2 = W[(k + 2) * 128 + t];
            const float w3 = W[(k + 3) * 128 + t];
            #pragma unroll
            for (int r = 0; r < 8; ++r) {
                const float4 xv = *reinterpret_cast<const float4*>(&xl[r * 128 + k]);
                acc[r] += xv.x * w0 + xv.y * w1 + xv.z * w2 + xv.w * w3;
            }
        }
        #pragma unroll
        for (int r = 0; r < 8; ++r) xw[r * 128 + t] = acc[r];
    }
    __syncthreads();

    if (t < 128) {
        const int b = row0 >> 11, n0 = row0 & 2047;
        bf16x8 st;
        #pragma unroll
        for (int r = 0; r < 8; ++r) st[r] = (__bf16)xw[r * 128 + t];
        *reinterpret_cast<bf16x8*>(&wxT[((size_t)(b * 128 + t)) * 2048 + n0]) = st;

        const int r = t >> 4, h = (t >> 1) & 7, s = t & 1;
        float dot = 0.f;
        #pragma unroll
        for (int d = 0; d < 16; ++d)
            dot += xw[r * 128 + h * 16 + d] * a[h * 32 + s * 16 + d];
        const float ef  = __expf(dot);
        const float ef5 = __expf(0.2f * dot);
        const int idx = (b * 8 + h) * 2048 + n0 + r;
        if (s) { EjT[idx] = ef; Ej5T[idx] = ef5; }
        else   { float2 ev; ev.x = ef; ev.y = ef5; EI[idx] = ev; }
    }
}

// bits[row][32] -> tmask[tileId][jtw][16]; word(kk,e) bit l =
//   adj[tile*16 + (l&15)][jtw*64 + kk*32 + (l>>4)*8 + e]
// Coalesced: wave loads its tile's 4KB contiguously, transposes via LDS+ballot.
__global__ __launch_bounds__(256)
void tpose_kernel(const u64* __restrict__ bits, u64* __restrict__ tmask)
{
    __shared__ u64 lb[4][16][32];
    const int wv = threadIdx.x >> 6, lane = threadIdx.x & 63;
    const int tileId = blockIdx.x * 4 + wv;  // 0..511 = b*128 + tile
    const u64* src = bits + (size_t)tileId * 512;
    #pragma unroll
    for (int i = 0; i < 8; ++i) {
        const int idx = i * 64 + lane;
        lb[wv][idx >> 5][idx & 31] = src[idx];
    }
    __syncthreads();
    const int rsel = lane & 15, shb = (lane >> 4) * 8;
    u64* dst = tmask + (size_t)tileId * 512;
    for (int jtw = 0; jtw < 32; ++jtw) {
        const u64 mw = lb[wv][rsel][jtw];
        u64 w[16];
        #pragma unroll
        for (int kk = 0; kk < 2; ++kk)
            #pragma unroll
            for (int e = 0; e < 8; ++e)
                w[kk * 8 + e] = __ballot(((mw >> (kk * 32 + shb + e)) & 1ull) != 0);
        #pragma unroll
        for (int k = 0; k < 16; ++k)       // static index; lanes 0..15 write
            if (lane == k) dst[jtw * 16 + k] = w[k];
    }
}

__global__ __launch_bounds__(512, 4)
void gat_kernel(const u64* __restrict__ tmask,
                const unsigned short* __restrict__ wxT,
                const float2* __restrict__ EI,
                const float* __restrict__ EjT, const float* __restrict__ Ej5T,
                const float* __restrict__ WoT, const float* __restrict__ bo,
                float* __restrict__ out)
{
    const int tid = threadIdx.x;
    const int h = tid >> 6;              // wave = head
    const int lane = tid & 63;
    const int r = lane & 15;             // A-frag row / B-frag col
    const int jg = lane >> 4;
    const int jaof = jg * 8;
    const u64 lanebit = 1ull << lane;
    // XCD-aware bijective swizzle (512 % 8 == 0)
    const int bid = (blockIdx.x & 7) * 64 + (blockIdx.x >> 3);
    const int b = bid >> 7;
    const int tile = bid & 127;
    const int ibase = tile << 4;

    // LDS: 32KB V (double-buffered, slot-swizzled) + 8KB Ej/Ej5 + 8KB hacc
    __shared__ __align__(16) unsigned short VL[2][8][1024];
    __shared__ __align__(16) float EjL[2][8][64];
    __shared__ __align__(16) float Ej5L[2][8][64];
    __shared__ float hacc[16][128];

    const int eb = (b * 8 + h) * 2048;
    const float2 q0 = EI[eb + ibase + r];
    f32x2 EiE, Ei5E;
    EiE[0] = q0.x; EiE[1] = q0.x; Ei5E[0] = q0.y; Ei5E[1] = q0.y;
    const u64* tmrow = tmask + (size_t)(b * 128 + tile) * 512;

    // staging roles: V -> 1024 slots of 16B (2/thread), Ej/Ej5 -> 1 f32 each
    const int h2 = tid >> 6, jj = tid & 63;
    const int uA = tid,        hA = uA >> 7, remA = uA & 127;
    const int fA = remA >> 3,  jbpA = remA & 7, jbA = jbpA ^ (fA & 7);
    const int uB = tid + 512,  hB = uB >> 7, remB = uB & 127;
    const int fB = remB >> 3,  jbpB = remB & 7, jbB = jbpB ^ (fB & 7);
    const unsigned short* wxb = wxT + (size_t)(b * 128) * 2048;
    const float* EjG  = EjT  + (b * 8 + h2) * 2048;
    const float* Ej5G = Ej5T + (b * 8 + h2) * 2048;

    f32x4 acc  = {0.f, 0.f, 0.f, 0.f};
    f32x4 accS = {0.f, 0.f, 0.f, 0.f};
    bf16x8 ones;
    #pragma unroll
    for (int e2 = 0; e2 < 8; ++e2) ones[e2] = (__bf16)1.0f;

    bf16x8 sv0, sv1; float se, se5;
    // ---- prologue: stage chunk 0 -> buf 0
    {
        const int j0 = 0;
        sv0 = *reinterpret_cast<const bf16x8*>(
                  &wxb[(size_t)(hA * 16 + fA) * 2048 + j0 + jbA * 8]);
        sv1 = *reinterpret_cast<const bf16x8*>(
                  &wxb[(size_t)(hB * 16 + fB) * 2048 + j0 + jbB * 8]);
        se  = EjG[j0 + jj];
        se5 = Ej5G[j0 + jj];
        *reinterpret_cast<bf16x8*>(&VL[0][hA][fA * 64 + jbpA * 8]) = sv0;
        *reinterpret_cast<bf16x8*>(&VL[0][hB][fB * 64 + jbpB * 8]) = sv1;
        EjL[0][h2][jj] = se;
        Ej5L[0][h2][jj] = se5;
    }
    __syncthreads();

    int cur = 0;
    for (int c = 0; c < 32; ++c) {
        // ---- issue next chunk's loads (wrap on last; discarded)
        const int j0n = ((c + 1) & 31) * 64;
        sv0 = *reinterpret_cast<const bf16x8*>(
                  &wxb[(size_t)(hA * 16 + fA) * 2048 + j0n + jbA * 8]);
        sv1 = *reinterpret_cast<const bf16x8*>(
                  &wxb[(size_t)(hB * 16 + fB) * 2048 + j0n + jbB * 8]);
        se  = EjG[j0n + jj];
        se5 = Ej5G[j0n + jj];

        // ---- masks (block-uniform address -> scalar loads)
        const u64* tmw = tmrow + c * 16;
        u64 mw[16];
        #pragma unroll
        for (int e2 = 0; e2 < 16; ++e2) mw[e2] = tmw[e2];

        // ---- compute current chunk from LDS
        #pragma unroll
        for (int kk = 0; kk < 2; ++kk) {
            const float4 e0 = *reinterpret_cast<const float4*>(&EjL[cur][h][kk * 32 + jaof]);
            const float4 e1 = *reinterpret_cast<const float4*>(&EjL[cur][h][kk * 32 + jaof + 4]);
            const float4 f0 = *reinterpret_cast<const float4*>(&Ej5L[cur][h][kk * 32 + jaof]);
            const float4 f1 = *reinterpret_cast<const float4*>(&Ej5L[cur][h][kk * 32 + jaof + 4]);
            const int slot = r * 8 + (((kk << 2) | jg) ^ (r & 7));
            const bf16x8 v = *reinterpret_cast<const bf16x8*>(&VL[cur][h][slot * 8]);
            bf16x8 afr;
            #pragma unroll
            for (int ep = 0; ep < 4; ++ep) {
                const float4 ejv = (ep & 2) ? e1 : e0;
                const float4 ej5 = (ep & 2) ? f1 : f0;
                f32x2 ejp, ej5p;
                if (ep & 1) { ejp[0]=ejv.z; ejp[1]=ejv.w; ej5p[0]=ej5.z; ej5p[1]=ej5.w; }
                else        { ejp[0]=ejv.x; ejp[1]=ejv.y; ej5p[0]=ej5.x; ej5p[1]=ej5.y; }
                const f32x2 t1 = EiE * ejp;        // {Ei*Ej0, Ei*Ej1}
                const f32x2 t2 = Ei5E * ej5p;      // {Ei5*Ej50, Ei5*Ej51}
#if __has_builtin(__builtin_elementwise_max)
                const f32x2 tm2 = __builtin_elementwise_max(t1, t2);
#else
                f32x2 tm2; tm2[0] = fmaxf(t1[0], t2[0]); tm2[1] = fmaxf(t1[1], t2[1]);
#endif
                afr[2 * ep]     = (__bf16)lsel(tm2[0], mw[kk * 8 + 2 * ep],     lanebit);
                afr[2 * ep + 1] = (__bf16)lsel(tm2[1], mw[kk * 8 + 2 * ep + 1], lanebit);
            }
            acc  = __builtin_amdgcn_mfma_f32_16x16x32_bf16(afr, v,    acc,  0, 0, 0);
            accS = __builtin_amdgcn_mfma_f32_16x16x32_bf16(afr, ones, accS, 0, 0, 0);
        }

        // ---- write staged regs to the other buffer (vmcnt lands here,
        //      after a full compute phase of cover), then one barrier
        const int nb = cur ^ 1;
        *reinterpret_cast<bf16x8*>(&VL[nb][hA][fA * 64 + jbpA * 8]) = sv0;
        *reinterpret_cast<bf16x8*>(&VL[nb][hB][fB * 64 + jbpB * 8]) = sv1;
        EjL[nb][h2][jj] = se;
        Ej5L[nb][h2][jj] = se5;
        __syncthreads();
        cur = nb;
    }

    // C/D layout: col = lane&15 (=feature r), row = jg*4+q. accS[q] = row sum.
    #pragma unroll
    for (int q = 0; q < 4; ++q) {
        const int row = jg * 4 + q;
        const float inv = (accS[q] > 0.f) ? 1.f / accS[q] : 0.f;  // empty row -> 0
        hacc[row][h * 16 + r] = acc[q] * inv;
    }
    __syncthreads();

    // ---- fused out-proj + ELU (r4-proven): 512 threads, 4 rows each
    const int f = tid & 127;
    const int rg = tid >> 7;  // 4 groups x 4 rows
    float o0 = 0.f, o1 = 0.f, o2 = 0.f, o3 = 0.f;
    for (int k = 0; k < 128; k += 4) {
        const float w0 = WoT[(k + 0) * 128 + f];
        const float w1 = WoT[(k + 1) * 128 + f];
        const float w2 = WoT[(k + 2) * 128 + f];
        const float w3 = WoT[(k + 3) * 128 + f];
        const float4 h0 = *reinterpret_cast<const float4*>(&hacc[rg * 4 + 0][k]);
        const float4 h1 = *reinterpret_cast<const float4*>(&hacc[rg * 4 + 1][k]);
        const float4 h2v = *reinterpret_cast<const float4*>(&hacc[rg * 4 + 2][k]);
        const float4 h3 = *reinterpret_cast<const float4*>(&hacc[rg * 4 + 3][k]);
        o0 += h0.x * w0 + h0.y * w1 + h0.z * w2 + h0.w * w3;
        o1 += h1.x * w0 + h1.y * w1 + h1.z * w2 + h1.w * w3;
        o2 += h2v.x * w0 + h2v.y * w1 + h2v.z * w2 + h2v.w * w3;
        o3 += h3.x * w0 + h3.y * w1 + h3.z * w2 + h3.w * w3;
    }
    const float bv = bo[f];
    float vv[4] = {o0 + bv, o1 + bv, o2 + bv, o3 + bv};
    #pragma unroll
    for (int q = 0; q < 4; ++q) {
        float v = vv[q];
        v = (v > 0.f) ? v : (__expf(v) - 1.f);
        out[(size_t)(b * 2048 + ibase + rg * 4 + q) * 128 + f] = v;
    }
}

extern "C" void kernel_launch(void* const* d_in, const int* in_sizes, int n_in,
                              void* d_out, int out_size, void* d_ws, size_t ws_size,
                              hipStream_t stream) {
    const float* x   = (const float*)d_in[0];
    const int*   adj = (const int*)d_in[1];
    const float* W   = (const float*)d_in[2];
    const float* a   = (const float*)d_in[3];
    const float* Wo  = (const float*)d_in[4];
    const float* bo  = (const float*)d_in[5];
    float* out = (float*)d_out;

    // ws: wxT 2MB | EI 512K | EjT 256K | Ej5T 256K | WoT 64K | bits 2MB | tmask 2MB
    char* ws = (char*)d_ws;
    unsigned short* wxT = (unsigned short*)ws;
    float2* EI  = (float2*)(ws + (size_t)2 * 1024 * 1024);
    float* EjT  = (float*)(EI + 4 * 8 * 2048);
    float* Ej5T = EjT + 4 * 8 * 2048;
    float* WoT  = Ej5T + 4 * 8 * 2048;
    u64* bits  = (u64*)(WoT + 128 * 128);
    u64* tmask = bits + (size_t)8192 * 32;

    prep_kernel<<<dim3(1025 + 2048), dim3(256), 0, stream>>>(
        x, W, a, Wo, adj, wxT, EI, EjT, Ej5T, WoT, bits);
    tpose_kernel<<<dim3(128), dim3(256), 0, stream>>>(bits, tmask);
    gat_kernel<<<dim3(512), dim3(512), 0, stream>>>(
        tmask, wxT, EI, EjT, Ej5T, WoT, bo, out);
}

// Round 11
// 68.665 us; speedup vs baseline: 1.3029x; 1.3029x over previous
//
#include <hip/hip_runtime.h>
#include <hip/hip_bf16.h>
#include <cstdint>

// GAT fused layer: B=4, N=2048, F=128, H=8, HD=16, all fp32 I/O.
// Identity: exp(leaky(si+sj)) = max(exp(si)exp(sj), exp(.2si)exp(.2sj))
// prep: blocks [0,1024) proj (XW -> WxT bf16 + exp tables), block 1024 WoT,
//   blocks [1025,3073) tpack: adj -> TRANSPOSED u64 mask words DIRECTLY
//   (stage 16x256 adj ints in padded LDS coalesced, ballot per jtw, one
//   coalesced 128B store) -- replaces r10's pack+tpose pair (~30 us -> HBM floor).
// gat (r10 structure): LDS-staged 2-phase pipeline; per chunk of 64 j:
//   {issue next loads (pinned early w/ sched_barrier) | compute from LDS |
//   ds_write other buffer | barrier}. Masks: wave-uniform s_load +
//   inverse_ballot. Aggregation + row-sum via mfma_f32_16x16x32_bf16
//   (B=ones). Fused out-proj + ELU.

typedef float f32x2 __attribute__((ext_vector_type(2)));
typedef float f32x4 __attribute__((ext_vector_type(4)));
typedef __bf16 bf16x8 __attribute__((ext_vector_type(8)));
typedef unsigned long long u64;

__device__ __forceinline__ float lsel(float v, u64 m, u64 lanebit) {
#if __has_builtin(__builtin_amdgcn_inverse_ballot_w64)
    (void)lanebit;
    return __builtin_amdgcn_inverse_ballot_w64(m) ? v : 0.0f;
#else
    return (m & lanebit) ? v : 0.0f;
#endif
}

__global__ __launch_bounds__(256)
void prep_kernel(const float* __restrict__ x, const float* __restrict__ W,
                 const float* __restrict__ a, const float* __restrict__ Wo,
                 const int* __restrict__ adj,
                 unsigned short* __restrict__ wxT,
                 float2* __restrict__ EI,
                 float* __restrict__ EjT, float* __restrict__ Ej5T,
                 float* __restrict__ WoT,
                 u64* __restrict__ tmask)
{
    const int t = threadIdx.x;

    if (blockIdx.x >= 1025) {
        // ---- tpack: adj -> transposed mask words, 2048 blocks = (b,tile,jq)
        __shared__ int al[16][257];   // padded: bank = (row+col)%32, ~2-way
        const int blk2 = blockIdx.x - 1025;
        const int b = blk2 >> 9;
        const int tile = (blk2 >> 2) & 127;
        const int jq = blk2 & 3;                 // 512-j quarter
        const int rowbase = b * 2048 + tile * 16;
        const int w = t >> 6, lane = t & 63;
        const int r = lane & 15, jg = lane >> 4;
        const int srow = t >> 4, scol = (t & 15) * 16;

        #pragma unroll
        for (int cc = 0; cc < 2; ++cc) {
            const int jc = jq * 512 + cc * 256;  // chunk of 256 j
            // stage 16 rows x 256 ints, coalesced
            const int* gsrc = adj + (size_t)(rowbase + srow) * 2048 + jc + scol;
            #pragma unroll
            for (int q = 0; q < 4; ++q) {
                const int4 v = *reinterpret_cast<const int4*>(&gsrc[q * 4]);
                al[srow][scol + q * 4 + 0] = v.x;
                al[srow][scol + q * 4 + 1] = v.y;
                al[srow][scol + q * 4 + 2] = v.z;
                al[srow][scol + q * 4 + 3] = v.w;
            }
            __syncthreads();
            // wave w -> jtw = jq*8 + cc*4 + w; 16 ballots, 1 coalesced store
            u64 myw = 0;
            #pragma unroll
            for (int kk = 0; kk < 2; ++kk) {
                const int c0 = w * 64 + kk * 32 + jg * 8;
                const int4 a0 = *reinterpret_cast<const int4*>(&al[r][c0]);
                const int4 a1 = *reinterpret_cast<const int4*>(&al[r][c0 + 4]);
                const int av[8] = {a0.x, a0.y, a0.z, a0.w, a1.x, a1.y, a1.z, a1.w};
                #pragma unroll
                for (int e = 0; e < 8; ++e) {
                    const u64 bal = __ballot(av[e] != 0);
                    const int widx = kk * 8 + e;
                    if (lane == widx) myw = bal;
                }
            }
            __syncthreads();  // reads done before next chunk overwrites LDS
            const int jtw = jq * 8 + cc * 4 + w;
            if (lane < 16)
                tmask[((size_t)(b * 128 + tile) * 32 + jtw) * 16 + lane] = myw;
        }
        return;
    }

    // ---- proj: blocks 0..1024 (t<128 active)
    const int blk = blockIdx.x;
    if (blk == 1024) {
        if (t < 128)
            for (int k = 0; k < 128; ++k)
                WoT[k * 128 + t] = Wo[t * 128 + k];
        return;
    }
    __shared__ float xl[8 * 128];
    __shared__ float xw[8 * 128];
    const int row0 = blk * 8;
    if (t < 128) {
        #pragma unroll
        for (int r = 0; r < 8; ++r)
            xl[r * 128 + t] = x[(size_t)(row0 + r) * 128 + t];
    }
    __syncthreads();

    if (t < 128) {
        float acc[8] = {0.f, 0.f, 0.f, 0.f, 0.f, 0.f, 0.f, 0.f};
        for (int k = 0; k < 128; k += 4) {
            const float w0 = W[(k + 0) * 128 + t];
            const float w1 = W[(k + 1) * 128 + t];
            const float w2 = W[(k + 2) * 128 + t];
            const float w3 = W[(k + 3) * 128 + t];
            #pragma unroll
            for (int r = 0; r < 8; ++r) {
                const float4 xv = *reinterpret_cast<const float4*>(&xl[r * 128 + k]);
                acc[r] += xv.x * w0 + xv.y * w1 + xv.z * w2 + xv.w * w3;
            }
        }
        #pragma unroll
        for (int r = 0; r < 8; ++r) xw[r * 128 + t] = acc[r];
    }
    __syncthreads();

    if (t < 128) {
        const int b = row0 >> 11, n0 = row0 & 2047;
        bf16x8 st;
        #pragma unroll
        for (int r = 0; r < 8; ++r) st[r] = (__bf16)xw[r * 128 + t];
        *reinterpret_cast<bf16x8*>(&wxT[((size_t)(b * 128 + t)) * 2048 + n0]) = st;

        const int r = t >> 4, h = (t >> 1) & 7, s = t & 1;
        float dot = 0.f;
        #pragma unroll
        for (int d = 0; d < 16; ++d)
            dot += xw[r * 128 + h * 16 + d] * a[h * 32 + s * 16 + d];
        const float ef  = __expf(dot);
        const float ef5 = __expf(0.2f * dot);
        const int idx = (b * 8 + h) * 2048 + n0 + r;
        if (s) { EjT[idx] = ef; Ej5T[idx] = ef5; }
        else   { float2 ev; ev.x = ef; ev.y = ef5; EI[idx] = ev; }
    }
}

__global__ __launch_bounds__(512, 4)
void gat_kernel(const u64* __restrict__ tmask,
                const unsigned short* __restrict__ wxT,
                const float2* __restrict__ EI,
                const float* __restrict__ EjT, const float* __restrict__ Ej5T,
                const float* __restrict__ WoT, const float* __restrict__ bo,
                float* __restrict__ out)
{
    const int tid = threadIdx.x;
    const int h = tid >> 6;              // wave = head
    const int lane = tid & 63;
    const int r = lane & 15;             // A-frag row / B-frag col
    const int jg = lane >> 4;
    const int jaof = jg * 8;
    const u64 lanebit = 1ull << lane;
    // XCD-aware bijective swizzle (512 % 8 == 0)
    const int bid = (blockIdx.x & 7) * 64 + (blockIdx.x >> 3);
    const int b = bid >> 7;
    const int tile = bid & 127;
    const int ibase = tile << 4;

    __shared__ __align__(16) unsigned short VL[2][8][1024];
    __shared__ __align__(16) float EjL[2][8][64];
    __shared__ __align__(16) float Ej5L[2][8][64];
    __shared__ float hacc[16][128];

    const int eb = (b * 8 + h) * 2048;
    const float2 q0 = EI[eb + ibase + r];
    f32x2 EiE, Ei5E;
    EiE[0] = q0.x; EiE[1] = q0.x; Ei5E[0] = q0.y; Ei5E[1] = q0.y;
    const u64* tmrow = tmask + (size_t)(b * 128 + tile) * 512;

    const int h2 = tid >> 6, jj = tid & 63;
    const int uA = tid,        hA = uA >> 7, remA = uA & 127;
    const int fA = remA >> 3,  jbpA = remA & 7, jbA = jbpA ^ (fA & 7);
    const int uB = tid + 512,  hB = uB >> 7, remB = uB & 127;
    const int fB = remB >> 3,  jbpB = remB & 7, jbB = jbpB ^ (fB & 7);
    const unsigned short* wxb = wxT + (size_t)(b * 128) * 2048;
    const float* EjG  = EjT  + (b * 8 + h2) * 2048;
    const float* Ej5G = Ej5T + (b * 8 + h2) * 2048;

    f32x4 acc  = {0.f, 0.f, 0.f, 0.f};
    f32x4 accS = {0.f, 0.f, 0.f, 0.f};
    bf16x8 ones;
    #pragma unroll
    for (int e2 = 0; e2 < 8; ++e2) ones[e2] = (__bf16)1.0f;

    bf16x8 sv0, sv1; float se, se5;
    // ---- prologue: stage chunk 0 -> buf 0
    {
        const int j0 = 0;
        sv0 = *reinterpret_cast<const bf16x8*>(
                  &wxb[(size_t)(hA * 16 + fA) * 2048 + j0 + jbA * 8]);
        sv1 = *reinterpret_cast<const bf16x8*>(
                  &wxb[(size_t)(hB * 16 + fB) * 2048 + j0 + jbB * 8]);
        se  = EjG[j0 + jj];
        se5 = Ej5G[j0 + jj];
        *reinterpret_cast<bf16x8*>(&VL[0][hA][fA * 64 + jbpA * 8]) = sv0;
        *reinterpret_cast<bf16x8*>(&VL[0][hB][fB * 64 + jbpB * 8]) = sv1;
        EjL[0][h2][jj] = se;
        Ej5L[0][h2][jj] = se5;
    }
    __syncthreads();

    int cur = 0;
    for (int c = 0; c < 32; ++c) {
        // ---- issue next chunk's loads; pin issue HERE (sched_barrier stops
        //      the compiler from sinking them to the ds_write below)
        const int j0n = ((c + 1) & 31) * 64;
        sv0 = *reinterpret_cast<const bf16x8*>(
                  &wxb[(size_t)(hA * 16 + fA) * 2048 + j0n + jbA * 8]);
        sv1 = *reinterpret_cast<const bf16x8*>(
                  &wxb[(size_t)(hB * 16 + fB) * 2048 + j0n + jbB * 8]);
        se  = EjG[j0n + jj];
        se5 = Ej5G[j0n + jj];
        __builtin_amdgcn_sched_barrier(0);

        // ---- masks (block-uniform address -> scalar loads)
        const u64* tmw = tmrow + c * 16;
        u64 mw[16];
        #pragma unroll
        for (int e2 = 0; e2 < 16; ++e2) mw[e2] = tmw[e2];

        // ---- compute current chunk from LDS
        #pragma unroll
        for (int kk = 0; kk < 2; ++kk) {
            const float4 e0 = *reinterpret_cast<const float4*>(&EjL[cur][h][kk * 32 + jaof]);
            const float4 e1 = *reinterpret_cast<const float4*>(&EjL[cur][h][kk * 32 + jaof + 4]);
            const float4 f0 = *reinterpret_cast<const float4*>(&Ej5L[cur][h][kk * 32 + jaof]);
            const float4 f1 = *reinterpret_cast<const float4*>(&Ej5L[cur][h][kk * 32 + jaof + 4]);
            const int slot = r * 8 + (((kk << 2) | jg) ^ (r & 7));
            const bf16x8 v = *reinterpret_cast<const bf16x8*>(&VL[cur][h][slot * 8]);
            bf16x8 afr;
            #pragma unroll
            for (int ep = 0; ep < 4; ++ep) {
                const float4 ejv = (ep & 2) ? e1 : e0;
                const float4 ej5 = (ep & 2) ? f1 : f0;
                f32x2 ejp, ej5p;
                if (ep & 1) { ejp[0]=ejv.z; ejp[1]=ejv.w; ej5p[0]=ej5.z; ej5p[1]=ej5.w; }
                else        { ejp[0]=ejv.x; ejp[1]=ejv.y; ej5p[0]=ej5.x; ej5p[1]=ej5.y; }
                const f32x2 t1 = EiE * ejp;
                const f32x2 t2 = Ei5E * ej5p;
#if __has_builtin(__builtin_elementwise_max)
                const f32x2 tm2 = __builtin_elementwise_max(t1, t2);
#else
                f32x2 tm2; tm2[0] = fmaxf(t1[0], t2[0]); tm2[1] = fmaxf(t1[1], t2[1]);
#endif
                afr[2 * ep]     = (__bf16)lsel(tm2[0], mw[kk * 8 + 2 * ep],     lanebit);
                afr[2 * ep + 1] = (__bf16)lsel(tm2[1], mw[kk * 8 + 2 * ep + 1], lanebit);
            }
            acc  = __builtin_amdgcn_mfma_f32_16x16x32_bf16(afr, v,    acc,  0, 0, 0);
            accS = __builtin_amdgcn_mfma_f32_16x16x32_bf16(afr, ones, accS, 0, 0, 0);
        }

        // ---- write staged regs to the other buffer, one barrier
        const int nb = cur ^ 1;
        *reinterpret_cast<bf16x8*>(&VL[nb][hA][fA * 64 + jbpA * 8]) = sv0;
        *reinterpret_cast<bf16x8*>(&VL[nb][hB][fB * 64 + jbpB * 8]) = sv1;
        EjL[nb][h2][jj] = se;
        Ej5L[nb][h2][jj] = se5;
        __syncthreads();
        cur = nb;
    }

    // C/D layout: col = lane&15 (=feature r), row = jg*4+q. accS[q] = row sum.
    #pragma unroll
    for (int q = 0; q < 4; ++q) {
        const int row = jg * 4 + q;
        const float inv = (accS[q] > 0.f) ? 1.f / accS[q] : 0.f;  // empty row -> 0
        hacc[row][h * 16 + r] = acc[q] * inv;
    }
    __syncthreads();

    // ---- fused out-proj + ELU: 512 threads, 4 rows each
    const int f = tid & 127;
    const int rg = tid >> 7;
    float o0 = 0.f, o1 = 0.f, o2 = 0.f, o3 = 0.f;
    for (int k = 0; k < 128; k += 4) {
        const float w0 = WoT[(k + 0) * 128 + f];
        const float w1 = WoT[(k + 1) * 128 + f];
        const float w2 = WoT[(k + 2) * 128 + f];
        const float w3 = WoT[(k + 3) * 128 + f];
        const float4 h0 = *reinterpret_cast<const float4*>(&hacc[rg * 4 + 0][k]);
        const float4 h1 = *reinterpret_cast<const float4*>(&hacc[rg * 4 + 1][k]);
        const float4 h2v = *reinterpret_cast<const float4*>(&hacc[rg * 4 + 2][k]);
        const float4 h3 = *reinterpret_cast<const float4*>(&hacc[rg * 4 + 3][k]);
        o0 += h0.x * w0 + h0.y * w1 + h0.z * w2 + h0.w * w3;
        o1 += h1.x * w0 + h1.y * w1 + h1.z * w2 + h1.w * w3;
        o2 += h2v.x * w0 + h2v.y * w1 + h2v.z * w2 + h2v.w * w3;
        o3 += h3.x * w0 + h3.y * w1 + h3.z * w2 + h3.w * w3;
    }
    const float bv = bo[f];
    float vv[4] = {o0 + bv, o1 + bv, o2 + bv, o3 + bv};
    #pragma unroll
    for (int q = 0; q < 4; ++q) {
        float v = vv[q];
        v = (v > 0.f) ? v : (__expf(v) - 1.f);
        out[(size_t)(b * 2048 + ibase + rg * 4 + q) * 128 + f] = v;
    }
}

extern "C" void kernel_launch(void* const* d_in, const int* in_sizes, int n_in,
                              void* d_out, int out_size, void* d_ws, size_t ws_size,
                              hipStream_t stream) {
    const float* x   = (const float*)d_in[0];
    const int*   adj = (const int*)d_in[1];
    const float* W   = (const float*)d_in[2];
    const float* a   = (const float*)d_in[3];
    const float* Wo  = (const float*)d_in[4];
    const float* bo  = (const float*)d_in[5];
    float* out = (float*)d_out;

    // ws: wxT 2MB | EI 512K | EjT 256K | Ej5T 256K | WoT 64K | tmask 2MB
    char* ws = (char*)d_ws;
    unsigned short* wxT = (unsigned short*)ws;
    float2* EI  = (float2*)(ws + (size_t)2 * 1024 * 1024);
    float* EjT  = (float*)(EI + 4 * 8 * 2048);
    float* Ej5T = EjT + 4 * 8 * 2048;
    float* WoT  = Ej5T + 4 * 8 * 2048;
    u64* tmask = (u64*)(WoT + 128 * 128);

    prep_kernel<<<dim3(1025 + 2048), dim3(256), 0, stream>>>(
        x, W, a, Wo, adj, wxT, EI, EjT, Ej5T, WoT, tmask);
    gat_kernel<<<dim3(512), dim3(512), 0, stream>>>(
        tmask, wxT, EI, EjT, Ej5T, WoT, bo, out);
}